// Round 1
// 3338.615 us; speedup vs baseline: 1.2556x; 1.2556x over previous
//
#include <hip/hip_runtime.h>

// LSTMDecoder: B=1024, L=128, H=256, OUT=64, T=256, 2 layers.
// R11: 2-way gate-column split. 128 blocks (grid <= CU count, co-residency
// guaranteed); block pair (bid, bid^64) each computes half the h0/h1 columns
// -> per-CU weight stream halves: 768KB/step vs R10's 1.5MB/step at the
// ~64B/clk L1 return path that bounded R10 (24.6k of 39.6k cyc/step).
// Halves exchanged per layer per step via sc0/sc1 write-through payloads
// (4KB bf16, column-major) + device-scope relaxed atomic flags (monotonic,
// reset each launch by captured hipMemsetAsync). Waves 0-7: layer0 (+wave7
// h0 exchange, waves0-1 out-proj); waves 8-15: layer1 (hh during phase A,
// ih own-k-tiles while partner h0 is in flight, partner-k-tiles after).
// Weight prefetch now depth-4 (P0..P3, vmcnt(12)) so every phase's chunk
// count divides the rotation. Spin-guard bails after ~20ms -> fast fail,
// never a hang.

typedef float f32x4 __attribute__((ext_vector_type(4)));
typedef short bf16x8 __attribute__((ext_vector_type(8)));
typedef unsigned short u16;
typedef unsigned int u32;
typedef unsigned int u32x2 __attribute__((ext_vector_type(2)));
typedef unsigned int u32x4 __attribute__((ext_vector_type(4)));

// bf16 workspace layout (element offsets), swizzled:
// elem[((nt*KB + kt)*64 + lane)*8 + j] = W[nt*16 + (lane&15)][kt*32 + (lane>>4)*8 + j]
#define OFF_LH   0          // 32 tiles, KB=4
#define OFF_LC   65536      // 32 tiles, KB=4
#define OFF_IH0  131072     // 64 tiles, KB=4
#define OFF_HH0  262144     // 64 tiles, KB=8
#define OFF_IH1  524288     // 64 tiles, KB=8
#define OFF_HH1  786432     // 64 tiles, KB=8
#define OFF_OUT  1048576    // 4 tiles,  KB=8

// comm region (BYTE offsets into ws). Weights end at 2,129,920 B.
#define COMM_B   2228224
#define OBOX_B(bid,kind,slot) (COMM_B + ((((bid)*2+(kind))*2+(slot)) << 12))
#define FLAG_B   (COMM_B + 2097152)          // 4,325,376
#define FLAG_OFF(bid,kind) (FLAG_B + (((bid)*2+(kind))*4))
#define SPIN_LIMIT (1<<16)

__device__ __forceinline__ u16 f2bf(float x){
  unsigned u = __builtin_bit_cast(unsigned, x);
  return (u16)((u + 0x7fffu + ((u >> 16) & 1u)) >> 16);  // RNE
}

__global__ __launch_bounds__(256) void convert_swizzle(
    const float* __restrict__ src, u16* __restrict__ dst,
    int ntiles, int kbshift)
{
  int idx = blockIdx.x * 256 + threadIdx.x;
  int kblocks = 1 << kbshift;
  int n = ntiles << (kbshift + 9);
  if (idx >= n) return;
  int j    = idx & 7;
  int lane = (idx >> 3) & 63;
  int t3   = idx >> 9;
  int kt   = t3 & (kblocks - 1);
  int nt   = t3 >> kbshift;
  int row  = nt * 16 + (lane & 15);
  int k    = kt * 32 + (lane >> 4) * 8 + j;
  dst[idx] = f2bf(src[row * (kblocks * 32) + k]);
}

__device__ __forceinline__ f32x4 mfma16(bf16x8 a, bf16x8 b, f32x4 c){
  return __builtin_amdgcn_mfma_f32_16x16x32_bf16(a, b, c, 0, 0, 0);
}
__device__ __forceinline__ bf16x8 ld8(const u16* p){ return *(const bf16x8*)p; }
__device__ __forceinline__ float sigm(float x){ return 1.f/(1.f + __expf(-x)); }
__device__ __forceinline__ float tanh_f(float x){ return 1.f - 2.f/(__expf(2.f*x) + 1.f); }

#define HST 264   // h LDS row stride (256 + 8 pad)

// Issue 4 tile-fragment loads (chunk = one kt, 4 gate tiles) into Q[0..3].
#define ISSUE4(Q, seg, kt) \
  asm volatile( \
    "global_load_dwordx4 %0, %4, %8\n\t" \
    "global_load_dwordx4 %1, %5, %8\n\t" \
    "global_load_dwordx4 %2, %6, %8\n\t" \
    "global_load_dwordx4 %3, %7, %8" \
    : "=&v"(Q[0]), "=&v"(Q[1]), "=&v"(Q[2]), "=&v"(Q[3]) \
    : "v"(voffW +           (u32)((kt)*1024)), \
      "v"(voffW + 131072u + (u32)((kt)*1024)), \
      "v"(voffW + 262144u + (u32)((kt)*1024)), \
      "v"(voffW + 393216u + (u32)((kt)*1024)), \
      "s"(seg) \
    : "memory")

// Depth-4: at consume time the 3 newer chunks (12 loads) may be outstanding.
#define WAITC(Q) \
  asm volatile("s_waitcnt vmcnt(12)" \
    : "+v"(Q[0]), "+v"(Q[1]), "+v"(Q[2]), "+v"(Q[3]) :: "memory")

#define MFMA4(afrag, Q) { \
  acc0 = mfma16(afrag, Q[0], acc0); \
  acc1 = mfma16(afrag, Q[1], acc1); \
  acc2 = mfma16(afrag, Q[2], acc2); \
  acc3 = mfma16(afrag, Q[3], acc3); }

// device-coherent payload ops (bypass non-coherent L1/L2; land in L3)
__device__ __forceinline__ void st8_sc(void* p, u32 lo, u32 hi){
  u32x2 v = {lo, hi};
  asm volatile("global_store_dwordx2 %0, %1, off sc0 sc1" :: "v"(p), "v"(v) : "memory");
}
__device__ __forceinline__ void ld64_sc(const void* p, u32x4* q){
  asm volatile(
    "global_load_dwordx4 %0, %4, off sc0 sc1\n\t"
    "global_load_dwordx4 %1, %5, off sc0 sc1\n\t"
    "global_load_dwordx4 %2, %6, off sc0 sc1\n\t"
    "global_load_dwordx4 %3, %7, off sc0 sc1\n\t"
    "s_waitcnt vmcnt(0)"
    : "=&v"(q[0]), "=&v"(q[1]), "=&v"(q[2]), "=&v"(q[3])
    : "v"(p), "v"((const char*)p+16), "v"((const char*)p+32), "v"((const char*)p+48)
    : "memory");
}

// scatter one partner half (column-major 128x16 bf16) into LDS h buffer
__device__ __forceinline__ void scatter_cols(u16* hdst, const u32x4* q, int gc){
  #pragma unroll
  for (int k2 = 0; k2 < 4; ++k2){
    hdst[(2*k2+0)*HST + gc]     = (u16)(q[0][k2] & 0xffffu);
    hdst[(2*k2+1)*HST + gc]     = (u16)(q[0][k2] >> 16);
    hdst[(8+2*k2+0)*HST + gc]   = (u16)(q[1][k2] & 0xffffu);
    hdst[(8+2*k2+1)*HST + gc]   = (u16)(q[1][k2] >> 16);
    hdst[(2*k2+0)*HST + gc+1]   = (u16)(q[2][k2] & 0xffffu);
    hdst[(2*k2+1)*HST + gc+1]   = (u16)(q[2][k2] >> 16);
    hdst[(8+2*k2+0)*HST + gc+1] = (u16)(q[3][k2] & 0xffffu);
    hdst[(8+2*k2+1)*HST + gc+1] = (u16)(q[3][k2] >> 16);
  }
}

__global__ __launch_bounds__(1024)
__attribute__((amdgpu_waves_per_eu(4, 4)))
void lstm_fused(
    const float* __restrict__ latent,
    const float* __restrict__ b_lh, const float* __restrict__ b_lc,
    const float* __restrict__ b_ih0, const float* __restrict__ b_hh0,
    const float* __restrict__ b_ih1, const float* __restrict__ b_hh1,
    const float* __restrict__ b_out,
    const u16* __restrict__ ws,
    u16* __restrict__ comm,
    float* __restrict__ out)
{
  __shared__ __attribute__((aligned(16))) u16 h0_s[2][16*HST];
  __shared__ __attribute__((aligned(16))) u16 h1_s[2][16*HST];
  __shared__ __attribute__((aligned(16))) u16 lat_s[16*136];

  const u16* __restrict__ w_lh  = ws + OFF_LH;
  const u16* __restrict__ w_lc  = ws + OFF_LC;
  const u16* __restrict__ w_ih0 = ws + OFF_IH0;
  const u16* __restrict__ w_hh0 = ws + OFF_HH0;
  const u16* __restrict__ w_ih1 = ws + OFF_IH1;
  const u16* __restrict__ w_hh1 = ws + OFF_HH1;
  const u16* __restrict__ w_out = ws + OFF_OUT;

  const int tid  = threadIdx.x;
  const int w    = tid >> 6;          // wave 0..15
  const int lane = tid & 63;
  const int col  = lane & 15;
  const int quad = lane >> 4;
  const int bid  = blockIdx.x;        // 0..127
  const int grp  = bid & 63;
  const int role = bid >> 6;          // 0 or 1: which half of h columns
  const int pbid = bid ^ 64;          // partner block (same XCD mod-8)
  const int bbase = grp * 16;
  const int hrow  = quad * 4;
  const int l8    = lane * 8;
  const int ctw   = w & 7;            // col-tile within our half
  const int ctg   = role * 8 + ctw;   // global col-tile 0..15
  const u32 voffW = (u32)(ctg * 8192 + lane * 16);
  const int hread = col * HST + quad * 8;
  const int k_own = 4 * role;         // k-tiles covering OUR h half
  const int k_par = 4 - 4 * role;     // k-tiles covering partner half
  const int pb    = (1 - role) * 128; // partner column base
  char* cm = (char*)comm;

  // ---- stage latent (bf16) ----
  for (int i = tid; i < 16*128; i += 1024){
    int b = i >> 7, k = i & 127;
    lat_s[b*136 + k] = f2bf(latent[(bbase + b)*128 + k]);
  }
  __syncthreads();

  bf16x8 latA[4];
  #pragma unroll
  for (int kt = 0; kt < 4; ++kt)
    latA[kt] = ld8(&lat_s[col*136 + kt*32 + quad*8]);

  // ---- prologue: gx0 / bias1 / c init / h(-1) full (each block computes all) ----
  f32x4 gx0[4] = {};
  float bias1[4] = {};
  float c0[4] = {}, c1[4] = {};

  { // h0(-1) tile w -> h0_s[1]
    float bias = b_lh[w*16 + col]; f32x4 a = {bias,bias,bias,bias};
    #pragma unroll
    for (int kt = 0; kt < 4; ++kt) a = mfma16(latA[kt], ld8(w_lh + ((w*4+kt)<<9) + l8), a);
    #pragma unroll
    for (int rr = 0; rr < 4; ++rr) h0_s[1][(hrow+rr)*HST + w*16 + col] = f2bf(a[rr]);
  }
  { // h1(-1) tile w -> h1_s[1]
    float bias = b_lh[256 + w*16 + col]; f32x4 a = {bias,bias,bias,bias};
    #pragma unroll
    for (int kt = 0; kt < 4; ++kt) a = mfma16(latA[kt], ld8(w_lh + (((16+w)*4+kt)<<9) + l8), a);
    #pragma unroll
    for (int rr = 0; rr < 4; ++rr) h1_s[1][(hrow+rr)*HST + w*16 + col] = f2bf(a[rr]);
  }
  if (w < 8){
    { float bias = b_lc[ctg*16 + col]; f32x4 a = {bias,bias,bias,bias};
      #pragma unroll
      for (int kt = 0; kt < 4; ++kt) a = mfma16(latA[kt], ld8(w_lc + ((ctg*4+kt)<<9) + l8), a);
      #pragma unroll
      for (int rr = 0; rr < 4; ++rr) c0[rr] = a[rr]; }
    #pragma unroll
    for (int g = 0; g < 4; ++g){
      const int nt = g*16 + ctg;
      float bias = b_ih0[nt*16 + col] + b_hh0[nt*16 + col];
      f32x4 a = {bias,bias,bias,bias};
      #pragma unroll
      for (int kt = 0; kt < 4; ++kt) a = mfma16(latA[kt], ld8(w_ih0 + ((nt*4+kt)<<9) + l8), a);
      gx0[g] = a;
    }
  } else {
    { float bias = b_lc[256 + ctg*16 + col]; f32x4 a = {bias,bias,bias,bias};
      #pragma unroll
      for (int kt = 0; kt < 4; ++kt) a = mfma16(latA[kt], ld8(w_lc + (((16+ctg)*4+kt)<<9) + l8), a);
      #pragma unroll
      for (int rr = 0; rr < 4; ++rr) c1[rr] = a[rr]; }
    #pragma unroll
    for (int g = 0; g < 4; ++g){
      const int nt = g*16 + ctg;
      bias1[g] = b_ih1[nt*16 + col] + b_hh1[nt*16 + col];
    }
  }
  const float bout = (w < 2) ? b_out[(2*role + w)*16 + col] : 0.f;

  // payload addressing
  const int poff = ((ctw*16 + col)*16 + hrow)*2;             // own-tile store offset
  char* ob_own = cm + OBOX_B(bid, (w < 8 ? 0 : 1), 0) + poff; // + (slot<<12)
  const char* pob0 = cm + OBOX_B(pbid, 0, 0) + lane*64;       // wave7 h0 fetch
  const char* pob1 = cm + OBOX_B(pbid, 1, 0) + lane*64;       // wave7 h1 fetch
  u32* f_my0 = (u32*)(cm + FLAG_OFF(bid, 0));
  u32* f_my1 = (u32*)(cm + FLAG_OFF(bid, 1));
  u32* f_pa0 = (u32*)(cm + FLAG_OFF(pbid, 0));
  u32* f_pa1 = (u32*)(cm + FLAG_OFF(pbid, 1));
  int dead = 0;

  __syncthreads();

  // ---- weight prefetch pipeline prologue: chunks 0..3 ----
  bf16x8 P0[4], P1[4], P2[4], P3[4];
  if (w < 8){
    ISSUE4(P0, w_hh0, 0); ISSUE4(P1, w_hh0, 1); ISSUE4(P2, w_hh0, 2); ISSUE4(P3, w_hh0, 3);
  } else {
    ISSUE4(P0, w_hh1, 0); ISSUE4(P1, w_hh1, 1); ISSUE4(P2, w_hh1, 2); ISSUE4(P3, w_hh1, 3);
  }

  for (int t = 0; t < 256; ++t){
    const int p = t & 1;
    const u16* h0p = h0_s[p ^ 1];
    u16*       h0c = h0_s[p];
    const u16* h1p = h1_s[p ^ 1];
    u16*       h1c = h1_s[p];
    bf16x8 a0;
    f32x4 acc0, acc1, acc2, acc3;

    // ======== phase A ========
    if (w < 8){
      // layer 0 (our half of gate cols): gates = gx0 + h0(t-1) @ w_hh0^T
      acc0 = gx0[0]; acc1 = gx0[1]; acc2 = gx0[2]; acc3 = gx0[3];
      WAITC(P0); a0 = ld8(&h0p[hread + 0*32]); MFMA4(a0, P0); ISSUE4(P0, w_hh0, 4);
      WAITC(P1); a0 = ld8(&h0p[hread + 1*32]); MFMA4(a0, P1); ISSUE4(P1, w_hh0, 5);
      WAITC(P2); a0 = ld8(&h0p[hread + 2*32]); MFMA4(a0, P2); ISSUE4(P2, w_hh0, 6);
      WAITC(P3); a0 = ld8(&h0p[hread + 3*32]); MFMA4(a0, P3); ISSUE4(P3, w_hh0, 7);
      WAITC(P0); a0 = ld8(&h0p[hread + 4*32]); MFMA4(a0, P0); ISSUE4(P0, w_hh0, 0); // next step
      WAITC(P1); a0 = ld8(&h0p[hread + 5*32]); MFMA4(a0, P1); ISSUE4(P1, w_hh0, 1); // next step
      WAITC(P2); a0 = ld8(&h0p[hread + 6*32]); MFMA4(a0, P2); ISSUE4(P2, w_hh0, 2); // next step
      WAITC(P3); a0 = ld8(&h0p[hread + 7*32]); MFMA4(a0, P3); ISSUE4(P3, w_hh0, 3); // next step
      u16 hu[4];
      #pragma unroll
      for (int rr = 0; rr < 4; ++rr){
        float ii = sigm(acc0[rr]);
        float ff = sigm(acc1[rr]);
        float gg = tanh_f(acc2[rr]);
        float oo = sigm(acc3[rr]);
        float c = ff*c0[rr] + ii*gg;
        c0[rr] = c;
        u16 hb = f2bf(oo * tanh_f(c));
        h0c[(hrow+rr)*HST + ctg*16 + col] = hb;
        hu[rr] = hb;
      }
      st8_sc(ob_own + (p << 12), (u32)hu[0] | ((u32)hu[1] << 16),
                                 (u32)hu[2] | ((u32)hu[3] << 16));
    } else {
      // layer 1 hh part: bias1 + h1(t-1) @ w_hh1^T (chunks 0..7 of 16)
      acc0 = (f32x4){bias1[0],bias1[0],bias1[0],bias1[0]};
      acc1 = (f32x4){bias1[1],bias1[1],bias1[1],bias1[1]};
      acc2 = (f32x4){bias1[2],bias1[2],bias1[2],bias1[2]};
      acc3 = (f32x4){bias1[3],bias1[3],bias1[3],bias1[3]};
      WAITC(P0); a0 = ld8(&h1p[hread + 0*32]); MFMA4(a0, P0); ISSUE4(P0, w_hh1, 4);
      WAITC(P1); a0 = ld8(&h1p[hread + 1*32]); MFMA4(a0, P1); ISSUE4(P1, w_hh1, 5);
      WAITC(P2); a0 = ld8(&h1p[hread + 2*32]); MFMA4(a0, P2); ISSUE4(P2, w_hh1, 6);
      WAITC(P3); a0 = ld8(&h1p[hread + 3*32]); MFMA4(a0, P3); ISSUE4(P3, w_hh1, 7);
      WAITC(P0); a0 = ld8(&h1p[hread + 4*32]); MFMA4(a0, P0); ISSUE4(P0, w_ih1, k_own+0);
      WAITC(P1); a0 = ld8(&h1p[hread + 5*32]); MFMA4(a0, P1); ISSUE4(P1, w_ih1, k_own+1);
      WAITC(P2); a0 = ld8(&h1p[hread + 6*32]); MFMA4(a0, P2); ISSUE4(P2, w_ih1, k_own+2);
      WAITC(P3); a0 = ld8(&h1p[hread + 7*32]); MFMA4(a0, P3); ISSUE4(P3, w_ih1, k_own+3);
    }
    __syncthreads();   // bar1: own h0(t) half in LDS, payload stores drained

    // ======== phase B ========
    if (w >= 8){
      // ih on OUR k-half of h0(t) (already in LDS) while partner half is in flight
      WAITC(P0); a0 = ld8(&h0c[hread + (k_own+0)*32]); MFMA4(a0, P0); ISSUE4(P0, w_ih1, k_par+0);
      WAITC(P1); a0 = ld8(&h0c[hread + (k_own+1)*32]); MFMA4(a0, P1); ISSUE4(P1, w_ih1, k_par+1);
      WAITC(P2); a0 = ld8(&h0c[hread + (k_own+2)*32]); MFMA4(a0, P2); ISSUE4(P2, w_ih1, k_par+2);
      WAITC(P3); a0 = ld8(&h0c[hread + (k_own+3)*32]); MFMA4(a0, P3); ISSUE4(P3, w_ih1, k_par+3);
    } else if (w == 7){
      // h0 exchange: publish first, then consume (no circular wait)
      if (lane == 0)
        __hip_atomic_store(f_my0, (u32)(t+1), __ATOMIC_RELAXED, __HIP_MEMORY_SCOPE_AGENT);
      if (!dead){
        int g = 0;
        while (__hip_atomic_load(f_pa0, __ATOMIC_RELAXED, __HIP_MEMORY_SCOPE_AGENT) < (u32)(t+1)){
          if (++g > SPIN_LIMIT){ dead = 1; break; }
        }
      }
      __builtin_amdgcn_sched_barrier(0);
      u32x4 q[4];
      ld64_sc(pob0 + (p << 12), q);
      scatter_cols(h0c, q, pb + 2*lane);
    }
    __syncthreads();   // bar2: h0(t) full in LDS

    // ======== phase C ========
    if (w >= 8){
      WAITC(P0); a0 = ld8(&h0c[hread + (k_par+0)*32]); MFMA4(a0, P0); ISSUE4(P0, w_hh1, 0); // next step
      WAITC(P1); a0 = ld8(&h0c[hread + (k_par+1)*32]); MFMA4(a0, P1); ISSUE4(P1, w_hh1, 1); // next step
      WAITC(P2); a0 = ld8(&h0c[hread + (k_par+2)*32]); MFMA4(a0, P2); ISSUE4(P2, w_hh1, 2); // next step
      WAITC(P3); a0 = ld8(&h0c[hread + (k_par+3)*32]); MFMA4(a0, P3); ISSUE4(P3, w_hh1, 3); // next step
      u16 hu[4];
      #pragma unroll
      for (int rr = 0; rr < 4; ++rr){
        float ii = sigm(acc0[rr]);
        float ff = sigm(acc1[rr]);
        float gg = tanh_f(acc2[rr]);
        float oo = sigm(acc3[rr]);
        float c = ff*c1[rr] + ii*gg;
        c1[rr] = c;
        u16 hb = f2bf(oo * tanh_f(c));
        h1c[(hrow+rr)*HST + ctg*16 + col] = hb;
        hu[rr] = hb;
      }
      st8_sc(ob_own + (p << 12), (u32)hu[0] | ((u32)hu[1] << 16),
                                 (u32)hu[2] | ((u32)hu[3] << 16));
    }
    __syncthreads();   // bar3: own h1(t) half in LDS, payload drained

    // ======== phase D ========
    if (w == 7){
      // h1 exchange
      if (lane == 0)
        __hip_atomic_store(f_my1, (u32)(t+1), __ATOMIC_RELAXED, __HIP_MEMORY_SCOPE_AGENT);
      if (!dead){
        int g = 0;
        while (__hip_atomic_load(f_pa1, __ATOMIC_RELAXED, __HIP_MEMORY_SCOPE_AGENT) < (u32)(t+1)){
          if (++g > SPIN_LIMIT){ dead = 1; break; }
        }
      }
      __builtin_amdgcn_sched_barrier(0);
      u32x4 q[4];
      ld64_sc(pob1 + (p << 12), q);
      scatter_cols(h1c, q, pb + 2*lane);
    } else if (w < 2 && t > 0){
      // output projection for step t-1 (h1(t-1) is full), our half of OUT cols
      f32x4 oacc = {bout, bout, bout, bout};
      #pragma unroll
      for (int kt = 0; kt < 8; ++kt){
        bf16x8 af = ld8(&h1p[hread + kt*32]);
        oacc = mfma16(af, ld8(w_out + (((2*role + w)*8 + kt) << 9) + l8), oacc);
      }
      #pragma unroll
      for (int rr = 0; rr < 4; ++rr){
        int b = bbase + hrow + rr;
        __builtin_nontemporal_store(oacc[rr], &out[(b*256 + (t-1))*64 + (2*role + w)*16 + col]);
      }
    }
    __syncthreads();   // bar4: h1(t) full in LDS
  }

  // ---- epilogue: out(255) ----
  if (w < 2){
    const u16* h1f = h1_s[1];
    f32x4 oacc = {bout, bout, bout, bout};
    #pragma unroll
    for (int kt = 0; kt < 8; ++kt){
      bf16x8 af = ld8(&h1f[hread + kt*32]);
      oacc = mfma16(af, ld8(w_out + (((2*role + w)*8 + kt) << 9) + l8), oacc);
    }
    #pragma unroll
    for (int rr = 0; rr < 4; ++rr){
      int b = bbase + hrow + rr;
      __builtin_nontemporal_store(oacc[rr], &out[(b*256 + 255)*64 + (2*role + w)*16 + col]);
    }
  }
}

extern "C" void kernel_launch(void* const* d_in, const int* in_sizes, int n_in,
                              void* d_out, int out_size, void* d_ws, size_t ws_size,
                              hipStream_t stream)
{
  (void)in_sizes; (void)n_in; (void)out_size; (void)ws_size;
  const float* latent = (const float*)d_in[0];
  const float* w_lh   = (const float*)d_in[1];
  const float* b_lh   = (const float*)d_in[2];
  const float* w_lc   = (const float*)d_in[3];
  const float* b_lc   = (const float*)d_in[4];
  const float* w_ih0  = (const float*)d_in[5];
  const float* w_hh0  = (const float*)d_in[6];
  const float* b_ih0  = (const float*)d_in[7];
  const float* b_hh0  = (const float*)d_in[8];
  const float* w_ih1  = (const float*)d_in[9];
  const float* w_hh1  = (const float*)d_in[10];
  const float* b_ih1  = (const float*)d_in[11];
  const float* b_hh1  = (const float*)d_in[12];
  const float* w_out  = (const float*)d_in[13];
  const float* b_out  = (const float*)d_in[14];
  u16* ws = (u16*)d_ws;
  float* out = (float*)d_out;

  auto cvt = [&](const float* src, int off, int ntiles, int kbshift){
    int n = ntiles << (kbshift + 9);
    convert_swizzle<<<dim3((n + 255)/256), dim3(256), 0, stream>>>(src, ws + off, ntiles, kbshift);
  };
  cvt(w_lh,  OFF_LH,  32, 2);
  cvt(w_lc,  OFF_LC,  32, 2);
  cvt(w_ih0, OFF_IH0, 64, 2);
  cvt(w_hh0, OFF_HH0, 64, 3);
  cvt(w_ih1, OFF_IH1, 64, 3);
  cvt(w_hh1, OFF_HH1, 64, 3);
  cvt(w_out, OFF_OUT, 4, 3);

  // reset exchange flags (captured as a graph node; runs before the kernel
  // on every replay -> monotonic t+1 flags start from 0 each launch)
  hipMemsetAsync((char*)d_ws + FLAG_B, 0, 128*2*4, stream);

  lstm_fused<<<dim3(128), dim3(1024), 0, stream>>>(latent, b_lh, b_lc, b_ih0, b_hh0,
                                                   b_ih1, b_hh1, b_out, ws, ws, out);
}

// Round 4
// 2048.985 us; speedup vs baseline: 2.0459x; 1.6294x over previous
//
#include <hip/hip_runtime.h>

// LSTMDecoder: B=1024, L=128, H=256, OUT=64, T=256, 2 layers.
// R14: R13 + row-index fix. R13's absmax=0.84 was the LDS h-tile write
// missing the rt*16 row-base: each wave owns rows rt*16..+15 (rt=w&1) and
// every read/publish used rt*16, but h0c/h1c writes used (hrow+rr) only ->
// rt=1 waves clobbered rows 0-15 and rows 16-31 went stale in LDS. Fixed:
// (rt*16 + hrow + rr). Everything else unchanged from R13:
// weight-(semi-)stationary 8-way column split, 256 blocks x 512 thr
// (1/CU), w_hh1 slice (64KB) in LDS, hh0+ih1 streamed (256KB/step) via
// depth-4 inline-asm pipeline (uniform vmcnt(12) rotation), per-step
// all-gather of h0/h1 (2KB sc0/sc1 payloads + monotonic agent-scope
// flags, slot=t&1, memset-reset per launch), raw lgkm-only s_barrier so
// weight loads survive barriers, out written by s==0 blocks only,
// spin-guard -> fast wrong answer, never a hang.

typedef float f32x4 __attribute__((ext_vector_type(4)));
typedef short bf16x8 __attribute__((ext_vector_type(8)));
typedef unsigned short u16;
typedef unsigned int u32;
typedef unsigned int u32x4 __attribute__((ext_vector_type(4)));

// bf16 workspace layout (element offsets), swizzled:
// elem[((nt*KB + kt)*64 + lane)*8 + j] = W[nt*16 + (lane&15)][kt*32 + (lane>>4)*8 + j]
#define OFF_LH   0          // 32 tiles, KB=4
#define OFF_LC   65536      // 32 tiles, KB=4
#define OFF_IH0  131072     // 64 tiles, KB=4
#define OFF_HH0  262144     // 64 tiles, KB=8
#define OFF_IH1  524288     // 64 tiles, KB=8
#define OFF_HH1  786432     // 64 tiles, KB=8
#define OFF_OUT  1048576    // 4 tiles,  KB=8

// comm region (BYTE offsets into ws). Weights end at 2,129,920 B.
// payload slot = 2KB: 256 blocks x 2 kinds x 2 slots = 2MB.
#define COMM_B   2228224
#define OBOX(bid,kind,slot) (COMM_B + ((((bid)*2+(kind))*2+(slot)) << 11))
#define FLAG_B   (COMM_B + 2097152)
#define FLAG_OFF(bid,kind) (FLAG_B + (((bid)*2+(kind))*4))
#define SPIN_LIMIT (1<<15)
#define HST 264   // h LDS row stride in u16 (256 + 8 pad; 528B = 16B-aligned)

__device__ __forceinline__ u16 f2bf(float x){
  unsigned u = __builtin_bit_cast(unsigned, x);
  return (u16)((u + 0x7fffu + ((u >> 16) & 1u)) >> 16);  // RNE
}

__global__ __launch_bounds__(256) void convert_swizzle(
    const float* __restrict__ src, u16* __restrict__ dst,
    int ntiles, int kbshift)
{
  int idx = blockIdx.x * 256 + threadIdx.x;
  int kblocks = 1 << kbshift;
  int n = ntiles << (kbshift + 9);
  if (idx >= n) return;
  int j    = idx & 7;
  int lane = (idx >> 3) & 63;
  int t3   = idx >> 9;
  int kt   = t3 & (kblocks - 1);
  int nt   = t3 >> kbshift;
  int row  = nt * 16 + (lane & 15);
  int k    = kt * 32 + (lane >> 4) * 8 + j;
  dst[idx] = f2bf(src[row * (kblocks * 32) + k]);
}

__device__ __forceinline__ f32x4 mfma16(bf16x8 a, bf16x8 b, f32x4 c){
  return __builtin_amdgcn_mfma_f32_16x16x32_bf16(a, b, c, 0, 0, 0);
}
__device__ __forceinline__ bf16x8 ld8(const u16* p){ return *(const bf16x8*)p; }
__device__ __forceinline__ float sigm(float x){ return 1.f/(1.f + __expf(-x)); }
__device__ __forceinline__ float tanh_f(float x){ return 1.f - 2.f/(__expf(2.f*x) + 1.f); }

// Issue 4 tile-fragment loads (chunk = one kt, 4 gate tiles) into Q[0..3].
#define ISSUE4(Q, seg, kt) \
  asm volatile( \
    "global_load_dwordx4 %0, %4, %8\n\t" \
    "global_load_dwordx4 %1, %5, %8\n\t" \
    "global_load_dwordx4 %2, %6, %8\n\t" \
    "global_load_dwordx4 %3, %7, %8" \
    : "=&v"(Q[0]), "=&v"(Q[1]), "=&v"(Q[2]), "=&v"(Q[3]) \
    : "v"(voffW +           (u32)((kt)*1024)), \
      "v"(voffW + 131072u + (u32)((kt)*1024)), \
      "v"(voffW + 262144u + (u32)((kt)*1024)), \
      "v"(voffW + 393216u + (u32)((kt)*1024)), \
      "s"(seg) \
    : "memory")

// Depth-4: at consume time the 3 newer chunks (12 loads) may be outstanding.
#define WAITC(Q) \
  asm volatile("s_waitcnt vmcnt(12)" \
    : "+v"(Q[0]), "+v"(Q[1]), "+v"(Q[2]), "+v"(Q[3]) :: "memory")

#define MFMA4(afrag, Q) { \
  acc0 = mfma16(afrag, Q[0], acc0); \
  acc1 = mfma16(afrag, Q[1], acc1); \
  acc2 = mfma16(afrag, Q[2], acc2); \
  acc3 = mfma16(afrag, Q[3], acc3); }

// raw barrier: drain LDS ops only; weight loads stay in flight.
#define BARX() asm volatile("s_waitcnt lgkmcnt(0)\n\ts_barrier" ::: "memory")
#define VDRAIN() asm volatile("s_waitcnt vmcnt(0)" ::: "memory")

__device__ __forceinline__ u32 ldflag(const u32* p){
  return __hip_atomic_load(p, __ATOMIC_RELAXED, __HIP_MEMORY_SCOPE_AGENT);
}
__device__ __forceinline__ void stflag(u32* p, u32 v){
  __hip_atomic_store(p, v, __ATOMIC_RELAXED, __HIP_MEMORY_SCOPE_AGENT);
}
__device__ __forceinline__ void pub16(char* p, u32 v){
  asm volatile("global_store_short %0, %1, off sc0 sc1" :: "v"(p), "v"(v) : "memory");
}

// gather 1-2 partner payloads (2KB each, row-major [32 rows][32 cols] bf16)
// into the full-h LDS buffer. Caller guarantees this wave's vmem queue is
// empty on entry.
__device__ __forceinline__ void gather2(u16* hdst,
    const char* pay0, const char* pay1,
    const u32* pf0, const u32* pf1, int pcnt,
    int ps0, int ps1, int lane, u32 tgt, int* dead)
{
  if (!*dead){
    int gc = 0;
    for(;;){
      u32 a = ldflag(pf0);
      u32 b = (pcnt == 2) ? ldflag(pf1) : tgt;
      if (a >= tgt && b >= tgt) break;
      if (++gc > SPIN_LIMIT){ *dead = 1; break; }
    }
  }
  int base = (lane >> 1)*HST + (lane & 1)*16;
  u32x4 q0, q1, q2, q3;
  if (pcnt == 2){
    asm volatile(
      "global_load_dwordx4 %0, %4, off sc0 sc1\n\t"
      "global_load_dwordx4 %1, %5, off sc0 sc1\n\t"
      "global_load_dwordx4 %2, %6, off sc0 sc1\n\t"
      "global_load_dwordx4 %3, %7, off sc0 sc1"
      : "=&v"(q0), "=&v"(q1), "=&v"(q2), "=&v"(q3)
      : "v"(pay0), "v"(pay0+16), "v"(pay1), "v"(pay1+16)
      : "memory");
    asm volatile("s_waitcnt vmcnt(0)"
      : "+v"(q0), "+v"(q1), "+v"(q2), "+v"(q3) :: "memory");
    *(u32x4*)&hdst[base + ps0*32]     = q0;
    *(u32x4*)&hdst[base + ps0*32 + 8] = q1;
    *(u32x4*)&hdst[base + ps1*32]     = q2;
    *(u32x4*)&hdst[base + ps1*32 + 8] = q3;
  } else {
    asm volatile(
      "global_load_dwordx4 %0, %2, off sc0 sc1\n\t"
      "global_load_dwordx4 %1, %3, off sc0 sc1"
      : "=&v"(q0), "=&v"(q1)
      : "v"(pay0), "v"(pay0+16)
      : "memory");
    asm volatile("s_waitcnt vmcnt(0)" : "+v"(q0), "+v"(q1) :: "memory");
    *(u32x4*)&hdst[base + ps0*32]     = q0;
    *(u32x4*)&hdst[base + ps0*32 + 8] = q1;
  }
}

__global__ __launch_bounds__(512)
void lstm_fused(
    const float* __restrict__ latent,
    const float* __restrict__ b_lh, const float* __restrict__ b_lc,
    const float* __restrict__ b_ih0, const float* __restrict__ b_hh0,
    const float* __restrict__ b_ih1, const float* __restrict__ b_hh1,
    const float* __restrict__ b_out,
    const u16* __restrict__ ws,
    u16* __restrict__ comm,
    float* __restrict__ out)
{
  __shared__ __attribute__((aligned(16))) u16 h0f[2][32*HST];   // 2x16.5KB
  __shared__ __attribute__((aligned(16))) u16 h1f[2][32*HST];   // 2x16.5KB
  __shared__ __attribute__((aligned(16))) u16 hh1L[64*512];     // 64KB
  __shared__ __attribute__((aligned(16))) u16 lat_s[32*136];    // 8.5KB

  const u16* __restrict__ w_lh  = ws + OFF_LH;
  const u16* __restrict__ w_lc  = ws + OFF_LC;
  const u16* __restrict__ w_ih0 = ws + OFF_IH0;
  const u16* __restrict__ w_hh0 = ws + OFF_HH0;
  const u16* __restrict__ w_ih1 = ws + OFF_IH1;
  const u16* __restrict__ w_hh1 = ws + OFF_HH1;
  const u16* __restrict__ w_out = ws + OFF_OUT;

  const int tid  = threadIdx.x;
  const int w    = tid >> 6;          // wave 0..7
  const int lane = tid & 63;
  const int col  = lane & 15;
  const int quad = lane >> 4;
  const int bid  = blockIdx.x;        // 0..255
  const int s    = bid & 7;           // column slice
  const int g    = bid >> 3;          // batch group (32 rows)
  const int rt   = w & 1;             // row-tile within block (16 rows)
  const int hct  = (w >> 1) & 1;      // col-tile within slice (16 cols)
  const int hrow = quad * 4;
  const int l8   = lane * 8;
  const int ctb  = (s*2 + hct) * 16;  // global h-col base of our tile
  const u32 voffW = (u32)((s*2 + hct) * 8192 + lane * 16);
  const int hreadR = (rt*16 + col) * HST + quad * 8;
  char* cm = (char*)comm;

  // ---- stage latent (bf16) ----
  for (int i = tid; i < 32*128; i += 512){
    int b = i >> 7, k = i & 127;
    lat_s[b*136 + k] = f2bf(latent[(g*32 + b)*128 + k]);
  }
  __syncthreads();

  // ---- prologue ----
  // init h(-1) full (both layers, all 256 cols, our 32 rows): 64 tile-tasks
  #pragma unroll 1
  for (int i = 0; i < 8; ++i){
    int task = w*8 + i;
    int layer = task >> 5, rem = task & 31, rtq = rem >> 4, ct = rem & 15;
    int nt = layer*16 + ct;
    float bias = b_lh[nt*16 + col];
    f32x4 a = {bias, bias, bias, bias};
    #pragma unroll
    for (int kt = 0; kt < 4; ++kt){
      bf16x8 la = ld8(&lat_s[(rtq*16 + col)*136 + kt*32 + quad*8]);
      a = mfma16(la, ld8(w_lh + ((nt*4 + kt) << 9) + l8), a);
    }
    u16* dst = layer ? h1f[1] : h0f[1];
    #pragma unroll
    for (int rr = 0; rr < 4; ++rr)
      dst[(rtq*16 + hrow + rr)*HST + ct*16 + col] = f2bf(a[rr]);
  }

  // hh1 slice -> LDS (64KB): frag f=(gate*2+hctf)*8+kt at hh1L[f*512+lane*8]
  for (int i = tid; i < 4096; i += 512){
    int f = i >> 6, l = i & 63;
    int gate = f >> 4, hctf = (f >> 3) & 1, kt = f & 7;
    int nt = gate*16 + s*2 + hctf;
    *(bf16x8*)&hh1L[i*8] = ld8(w_hh1 + ((nt*8 + kt) << 9) + l*8);
  }

  bf16x8 latA[4];
  #pragma unroll
  for (int kt = 0; kt < 4; ++kt)
    latA[kt] = ld8(&lat_s[(rt*16 + col)*136 + kt*32 + quad*8]);

  f32x4 gx0[4] = {};
  float bias1[4] = {};
  float c0[4] = {}, c1[4] = {};
  float bo0 = 0.f, bo1 = 0.f;

  if (w < 4){
    { float bias = b_lc[ctb + col]; f32x4 a = {bias,bias,bias,bias};
      #pragma unroll
      for (int kt = 0; kt < 4; ++kt)
        a = mfma16(latA[kt], ld8(w_lc + (((s*2+hct)*4 + kt) << 9) + l8), a);
      #pragma unroll
      for (int rr = 0; rr < 4; ++rr) c0[rr] = a[rr]; }
    #pragma unroll
    for (int g_ = 0; g_ < 4; ++g_){
      int nt = g_*16 + s*2 + hct;
      float bias = b_ih0[nt*16 + col] + b_hh0[nt*16 + col];
      f32x4 a = {bias, bias, bias, bias};
      #pragma unroll
      for (int kt = 0; kt < 4; ++kt)
        a = mfma16(latA[kt], ld8(w_ih0 + ((nt*4 + kt) << 9) + l8), a);
      gx0[g_] = a;
    }
    bo0 = b_out[(hct*2 + 0)*16 + col];
    bo1 = b_out[(hct*2 + 1)*16 + col];
  } else {
    { float bias = b_lc[256 + ctb + col]; f32x4 a = {bias,bias,bias,bias};
      #pragma unroll
      for (int kt = 0; kt < 4; ++kt)
        a = mfma16(latA[kt], ld8(w_lc + (((16 + s*2+hct)*4 + kt) << 9) + l8), a);
      #pragma unroll
      for (int rr = 0; rr < 4; ++rr) c1[rr] = a[rr]; }
    #pragma unroll
    for (int g_ = 0; g_ < 4; ++g_){
      int nt = g_*16 + s*2 + hct;
      bias1[g_] = b_ih1[nt*16 + col] + b_hh1[nt*16 + col];
    }
  }

  // partner/payload addressing
  const int wl = w & 3;
  const int pcnt = (wl < 3) ? 2 : 1;
  int i0 = wl*2, i1 = wl*2 + 1;
  int ps0 = (i0 < s) ? i0 : i0 + 1;
  int ps1 = (i1 < s) ? i1 : i1 + 1;
  if (pcnt == 1) ps1 = ps0;
  const int kindm = (w < 4) ? 0 : 1;
  const char* ppay0 = cm + OBOX(g*8 + ps0, kindm, 0) + lane*32;
  const char* ppay1 = cm + OBOX(g*8 + ps1, kindm, 0) + lane*32;
  const u32* pf0 = (const u32*)(cm + FLAG_OFF(g*8 + ps0, kindm));
  const u32* pf1 = (const u32*)(cm + FLAG_OFF(g*8 + ps1, kindm));
  u32* fmy0 = (u32*)(cm + FLAG_OFF(bid, 0));
  u32* fmy1 = (u32*)(cm + FLAG_OFF(bid, 1));
  char* pub_own = cm + OBOX(bid, kindm, 0)
                + (((rt*16 + hrow)*32 + hct*16 + col) << 1);
  int dead = 0;

  __syncthreads();

  // ---- pipeline prologue: first 4 chunks ----
  bf16x8 Pq0[4], Pq1[4], Pq2[4], Pq3[4];
  if (w < 4){
    ISSUE4(Pq0, w_hh0, 0); ISSUE4(Pq1, w_hh0, 1);
    ISSUE4(Pq2, w_hh0, 2); ISSUE4(Pq3, w_hh0, 3);
  } else {
    ISSUE4(Pq0, w_ih1, 0); ISSUE4(Pq1, w_ih1, 1);
    ISSUE4(Pq2, w_ih1, 2); ISSUE4(Pq3, w_ih1, 3);
  }

  for (int t = 0; t < 256; ++t){
    const int p = t & 1;
    const u16* h0p = h0f[p ^ 1];
    u16*       h0c = h0f[p];
    const u16* h1p = h1f[p ^ 1];
    u16*       h1c = h1f[p];
    f32x4 acc0, acc1, acc2, acc3;
    bf16x8 a0;

    // ======== phase A ========
    if (w < 4){
      // layer 0: gates = gx0 + h0(t-1) @ w_hh0_slice^T
      acc0 = gx0[0]; acc1 = gx0[1]; acc2 = gx0[2]; acc3 = gx0[3];
      WAITC(Pq0); a0 = ld8(&h0p[hreadR + 0*32]); MFMA4(a0, Pq0); ISSUE4(Pq0, w_hh0, 4);
      WAITC(Pq1); a0 = ld8(&h0p[hreadR + 1*32]); MFMA4(a0, Pq1); ISSUE4(Pq1, w_hh0, 5);
      WAITC(Pq2); a0 = ld8(&h0p[hreadR + 2*32]); MFMA4(a0, Pq2); ISSUE4(Pq2, w_hh0, 6);
      WAITC(Pq3); a0 = ld8(&h0p[hreadR + 3*32]); MFMA4(a0, Pq3); ISSUE4(Pq3, w_hh0, 7);
      WAITC(Pq0); a0 = ld8(&h0p[hreadR + 4*32]); MFMA4(a0, Pq0); ISSUE4(Pq0, w_hh0, 0); // next step
      WAITC(Pq1); a0 = ld8(&h0p[hreadR + 5*32]); MFMA4(a0, Pq1); ISSUE4(Pq1, w_hh0, 1); // next step
      WAITC(Pq2); a0 = ld8(&h0p[hreadR + 6*32]); MFMA4(a0, Pq2); ISSUE4(Pq2, w_hh0, 2); // next step
      WAITC(Pq3); a0 = ld8(&h0p[hreadR + 7*32]); MFMA4(a0, Pq3); ISSUE4(Pq3, w_hh0, 3); // next step
      #pragma unroll
      for (int rr = 0; rr < 4; ++rr){
        float ii = sigm(acc0[rr]);
        float ff = sigm(acc1[rr]);
        float gg = tanh_f(acc2[rr]);
        float oo = sigm(acc3[rr]);
        float c = ff*c0[rr] + ii*gg;
        c0[rr] = c;
        u16 hb = f2bf(oo * tanh_f(c));
        h0c[(rt*16 + hrow + rr)*HST + ctb + col] = hb;   // FIXED: + rt*16
        pub16(pub_own + (p << 11) + rr*64, (u32)hb);
      }
      VDRAIN();   // retire payload stores (prefetched loads land in regs too)
    } else {
      // layer 1 hh part from LDS-resident w_hh1 (no vmem this phase)
      acc0 = (f32x4){bias1[0],bias1[0],bias1[0],bias1[0]};
      acc1 = (f32x4){bias1[1],bias1[1],bias1[1],bias1[1]};
      acc2 = (f32x4){bias1[2],bias1[2],bias1[2],bias1[2]};
      acc3 = (f32x4){bias1[3],bias1[3],bias1[3],bias1[3]};
      #pragma unroll
      for (int kt = 0; kt < 8; ++kt){
        bf16x8 af = ld8(&h1p[hreadR + kt*32]);
        acc0 = mfma16(af, ld8(&hh1L[((0*2 + hct)*8 + kt)*512 + l8]), acc0);
        acc1 = mfma16(af, ld8(&hh1L[((1*2 + hct)*8 + kt)*512 + l8]), acc1);
        acc2 = mfma16(af, ld8(&hh1L[((2*2 + hct)*8 + kt)*512 + l8]), acc2);
        acc3 = mfma16(af, ld8(&hh1L[((3*2 + hct)*8 + kt)*512 + l8]), acc3);
      }
    }
    BARX();   // bar1: own h0(t) tile in LDS, h0 payloads drained
    if (w == 4 && lane == 0) stflag(fmy0, (u32)(t+1));

    // ======== phase B: gather partner h0 halves (waves 0-3) ========
    if (w < 4)
      gather2(h0c, ppay0 + (p << 11), ppay1 + (p << 11),
              pf0, pf1, pcnt, ps0, ps1, lane, (u32)(t+1), &dead);
    BARX();   // bar2: h0(t) full in LDS

    // ======== phase C ========
    if (w >= 4){
      // layer 1 ih part: += h0(t) @ w_ih1_slice^T
      WAITC(Pq0); a0 = ld8(&h0c[hreadR + 0*32]); MFMA4(a0, Pq0); ISSUE4(Pq0, w_ih1, 4);
      WAITC(Pq1); a0 = ld8(&h0c[hreadR + 1*32]); MFMA4(a0, Pq1); ISSUE4(Pq1, w_ih1, 5);
      WAITC(Pq2); a0 = ld8(&h0c[hreadR + 2*32]); MFMA4(a0, Pq2); ISSUE4(Pq2, w_ih1, 6);
      WAITC(Pq3); a0 = ld8(&h0c[hreadR + 3*32]); MFMA4(a0, Pq3); ISSUE4(Pq3, w_ih1, 7);
      WAITC(Pq0); a0 = ld8(&h0c[hreadR + 4*32]); MFMA4(a0, Pq0); ISSUE4(Pq0, w_ih1, 0); // next step
      WAITC(Pq1); a0 = ld8(&h0c[hreadR + 5*32]); MFMA4(a0, Pq1); ISSUE4(Pq1, w_ih1, 1); // next step
      WAITC(Pq2); a0 = ld8(&h0c[hreadR + 6*32]); MFMA4(a0, Pq2); ISSUE4(Pq2, w_ih1, 2); // next step
      WAITC(Pq3); a0 = ld8(&h0c[hreadR + 7*32]); MFMA4(a0, Pq3); ISSUE4(Pq3, w_ih1, 3); // next step
      #pragma unroll
      for (int rr = 0; rr < 4; ++rr){
        float ii = sigm(acc0[rr]);
        float ff = sigm(acc1[rr]);
        float gg = tanh_f(acc2[rr]);
        float oo = sigm(acc3[rr]);
        float c = ff*c1[rr] + ii*gg;
        c1[rr] = c;
        u16 hb = f2bf(oo * tanh_f(c));
        h1c[(rt*16 + hrow + rr)*HST + ctb + col] = hb;   // FIXED: + rt*16
        pub16(pub_own + (p << 11) + rr*64, (u32)hb);
      }
      VDRAIN();   // retire h1 payload stores
    } else if (s == 0 && t > 0){
      // out-proj for step t-1 from full h1(t-1) (block s==0 only)
      f32x4 o0 = {bo0, bo0, bo0, bo0};
      f32x4 o1 = {bo1, bo1, bo1, bo1};
      #pragma unroll
      for (int kt = 0; kt < 8; ++kt){
        bf16x8 af = ld8(&h1p[hreadR + kt*32]);
        o0 = mfma16(af, ld8(w_out + (((hct*2 + 0)*8 + kt) << 9) + l8), o0);
        o1 = mfma16(af, ld8(w_out + (((hct*2 + 1)*8 + kt) << 9) + l8), o1);
      }
      #pragma unroll
      for (int rr = 0; rr < 4; ++rr){
        int b = g*32 + rt*16 + hrow + rr;
        __builtin_nontemporal_store(o0[rr], &out[(b*256 + (t-1))*64 + (hct*2+0)*16 + col]);
        __builtin_nontemporal_store(o1[rr], &out[(b*256 + (t-1))*64 + (hct*2+1)*16 + col]);
      }
    }
    BARX();   // bar3: own h1(t) tile in LDS, h1 payloads drained
    if (w == 0 && lane == 0) stflag(fmy1, (u32)(t+1));

    // ======== phase D: gather partner h1 halves (waves 4-7) ========
    if (w >= 4)
      gather2(h1c, ppay0 + (p << 11), ppay1 + (p << 11),
              pf0, pf1, pcnt, ps0, ps1, lane, (u32)(t+1), &dead);
    BARX();   // bar4: h1(t) full in LDS
  }

  // ---- epilogue: out(255) from h1f[1] (block s==0 only) ----
  if (s == 0 && w < 4){
    const u16* h1fin = h1f[1];
    f32x4 o0 = {bo0, bo0, bo0, bo0};
    f32x4 o1 = {bo1, bo1, bo1, bo1};
    #pragma unroll
    for (int kt = 0; kt < 8; ++kt){
      bf16x8 af = ld8(&h1fin[hreadR + kt*32]);
      o0 = mfma16(af, ld8(w_out + (((hct*2 + 0)*8 + kt) << 9) + l8), o0);
      o1 = mfma16(af, ld8(w_out + (((hct*2 + 1)*8 + kt) << 9) + l8), o1);
    }
    #pragma unroll
    for (int rr = 0; rr < 4; ++rr){
      int b = g*32 + rt*16 + hrow + rr;
      __builtin_nontemporal_store(o0[rr], &out[(b*256 + 255)*64 + (hct*2+0)*16 + col]);
      __builtin_nontemporal_store(o1[rr], &out[(b*256 + 255)*64 + (hct*2+1)*16 + col]);
    }
  }
}

extern "C" void kernel_launch(void* const* d_in, const int* in_sizes, int n_in,
                              void* d_out, int out_size, void* d_ws, size_t ws_size,
                              hipStream_t stream)
{
  (void)in_sizes; (void)n_in; (void)out_size; (void)ws_size;
  const float* latent = (const float*)d_in[0];
  const float* w_lh   = (const float*)d_in[1];
  const float* b_lh   = (const float*)d_in[2];
  const float* w_lc   = (const float*)d_in[3];
  const float* b_lc   = (const float*)d_in[4];
  const float* w_ih0  = (const float*)d_in[5];
  const float* w_hh0  = (const float*)d_in[6];
  const float* b_ih0  = (const float*)d_in[7];
  const float* b_hh0  = (const float*)d_in[8];
  const float* w_ih1  = (const float*)d_in[9];
  const float* w_hh1  = (const float*)d_in[10];
  const float* b_ih1  = (const float*)d_in[11];
  const float* b_hh1  = (const float*)d_in[12];
  const float* w_out  = (const float*)d_in[13];
  const float* b_out  = (const float*)d_in[14];
  u16* ws = (u16*)d_ws;
  float* out = (float*)d_out;

  auto cvt = [&](const float* src, int off, int ntiles, int kbshift){
    int n = ntiles << (kbshift + 9);
    convert_swizzle<<<dim3((n + 255)/256), dim3(256), 0, stream>>>(src, ws + off, ntiles, kbshift);
  };
  cvt(w_lh,  OFF_LH,  32, 2);
  cvt(w_lc,  OFF_LC,  32, 2);
  cvt(w_ih0, OFF_IH0, 64, 2);
  cvt(w_hh0, OFF_HH0, 64, 3);
  cvt(w_ih1, OFF_IH1, 64, 3);
  cvt(w_hh1, OFF_HH1, 64, 3);
  cvt(w_out, OFF_OUT, 4, 3);

  // reset exchange flags (captured as a graph node; runs before the kernel
  // on every replay -> monotonic t+1 flags start from 0 each launch)
  hipMemsetAsync((char*)d_ws + FLAG_B, 0, 256*2*4, stream);

  lstm_fused<<<dim3(256), dim3(512), 0, stream>>>(latent, b_lh, b_lc, b_ih0, b_hh0,
                                                  b_ih1, b_hh1, b_out, ws, ws, out);
}